// Round 16
// baseline (259.419 us; speedup 1.0000x reference)
//
#include <hip/hip_runtime.h>
#include <hip/hip_bf16.h>

#define BB 4
#define CC 64
#define NN 4096
#define HH 64
#define AH 256
#define KNN 16
#define EPSV 1e-5f
#define LOG2E 1.44269504088896f

#define KNN_BLKS 2048   // 2 queries/wave, 8/block
#define PF_BLKS 256     // 4 waves x 16 points = 64 points/block
#define PP_BLKS 32

typedef __attribute__((ext_vector_type(8))) short short8;
typedef __attribute__((ext_vector_type(4))) short short4v;
typedef __attribute__((ext_vector_type(4))) unsigned short ushort4v;
typedef __attribute__((ext_vector_type(4))) float floatx4;

__device__ __forceinline__ unsigned short f2bf(float f) {
    unsigned u = __float_as_uint(f);
    u += 0x7FFFu + ((u >> 16) & 1u);   // round-to-nearest-even
    return (unsigned short)(u >> 16);
}
__device__ __forceinline__ float bf2f(unsigned short u) {
    return __uint_as_float(((unsigned)u) << 16);
}
// packed RNE f32x2 -> bf16x2 (v_cvt_pk_bf16_f32 on gfx950)
__device__ __forceinline__ unsigned pkbf(float a, float b) {
    __hip_bfloat162 h = __float22bfloat162_rn(make_float2(a, b));
    return *(reinterpret_cast<unsigned*>(&h));
}
__device__ __forceinline__ unsigned long long umin64(unsigned long long a, unsigned long long b) {
    return a < b ? a : b;
}
__device__ __forceinline__ unsigned long long umax64(unsigned long long a, unsigned long long b) {
    return a > b ? a : b;
}
__device__ __forceinline__ unsigned long long shfl_xor_u64(unsigned long long v, int m) {
    int lo = __shfl_xor((int)(unsigned)(v & 0xFFFFFFFFull), m);
    int hi = __shfl_xor((int)(unsigned)(v >> 32), m);
    return ((unsigned long long)(unsigned)hi << 32) | (unsigned)lo;
}
// monotone signed-float -> unsigned mapping (norm-form distances can be <0)
__device__ __forceinline__ unsigned fmono(float d) {
    unsigned u = __float_as_uint(d);
    return ((int)u < 0) ? ~u : (u | 0x80000000u);
}

#define UPITCH 68
#define HPITCH 68

__device__ __forceinline__ short8 lds_frag(const unsigned short* p) {
    short4v lo = *(const short4v*)p;
    short4v hi = *(const short4v*)(p + 4);
    short8 v;
    v[0] = lo[0]; v[1] = lo[1]; v[2] = lo[2]; v[3] = lo[3];
    v[4] = hi[0]; v[5] = hi[1]; v[6] = hi[2]; v[7] = hi[3];
    return v;
}

// ---------------------------------------------------------------------------
// Feature tensors y1bf/keybf/qrybf are stored SWIZZLED: element for original
// column (nt*16 + mcol) lives at [point*64 + mcol*4 + nt] (b64 gathers).
// ---------------------------------------------------------------------------

// ---------------------------------------------------------------------------
// FUSED kernel: knn (blocks 0..2047) + prep_features (2048..2303) +
// param relayout (2304..2335). Unchanged from round 15 (verified).
// ---------------------------------------------------------------------------
__global__ __launch_bounds__(256, 3) void fused_prep_knn(
    const float* __restrict__ x, const float* __restrict__ y,
    const float* __restrict__ Ws, const float* __restrict__ bs,
    const float* __restrict__ Wk, const float* __restrict__ bk,
    const float* __restrict__ Wq, const float* __restrict__ bq,
    const float* __restrict__ P1, const float* __restrict__ pb1,
    const float* __restrict__ P2, const float* __restrict__ A1,
    const float* __restrict__ ab1, const float* __restrict__ A2,
    const float* __restrict__ g1, const float* __restrict__ b1v,
    const float* __restrict__ m1, const float* __restrict__ v1,
    const float* __restrict__ g2, const float* __restrict__ b2v,
    const float* __restrict__ m2, const float* __restrict__ v2,
    const float* __restrict__ Wend,
    int* __restrict__ idx_out,
    unsigned short* __restrict__ y1bf, unsigned short* __restrict__ keybf,
    unsigned short* __restrict__ qrybf,
    unsigned short* __restrict__ A1L, unsigned short* __restrict__ A2L,
    unsigned short* __restrict__ P2L, unsigned short* __restrict__ WendL,
    float* __restrict__ P1p, float* __restrict__ ab1f, float* __restrict__ bn2s_c) {
    __shared__ __align__(16) char smem[49152];   // 48 KB
    int blk = blockIdx.x;
    int lane = threadIdx.x & 63;
    int w = threadIdx.x >> 6;

    if (blk < KNN_BLKS) {
        // =================== KNN role: 2 queries per wave ===================
        float* px = (float*)smem;
        float* py = px + NN;
        float* pz = py + NN;
        unsigned long long* surv = (unsigned long long*)smem;  // alias

        int b = blk >> 9;
        int grp = blk & 511;
        const float* xb = x + (size_t)b * 3 * NN;
        for (int i = threadIdx.x; i < NN; i += 256) {
            px[i] = xb[i];
            py[i] = xb[NN + i];
            pz[i] = xb[2 * NN + i];
        }
        __syncthreads();

        int n0 = (grp << 3) + (w << 1);
        float q0x = px[n0], q0y = py[n0], q0z = pz[n0];
        float q1x = px[n0 + 1], q1y = py[n0 + 1], q1z = pz[n0 + 1];
        float q0w = q0x * q0x + q0y * q0y + q0z * q0z;
        float q1w = q1x * q1x + q1y * q1y + q1z * q1z;
        q0x *= -2.f; q0y *= -2.f; q0z *= -2.f;
        q1x *= -2.f; q1y *= -2.f; q1z *= -2.f;

        float d0reg[64], d1reg[64];
        float vmin0 = 3.4e38f, vmin1 = 3.4e38f;
#pragma unroll
        for (int r = 0; r < 16; ++r) {
            int c = r * 64 + lane;
            float4 cx = ((const float4*)px)[c];
            float4 cy = ((const float4*)py)[c];
            float4 cz = ((const float4*)pz)[c];
            float exv[4] = {cx.x, cx.y, cx.z, cx.w};
            float eyv[4] = {cy.x, cy.y, cy.z, cy.w};
            float ezv[4] = {cz.x, cz.y, cz.z, cz.w};
#pragma unroll
            for (int e = 0; e < 4; ++e) {
                float nx = exv[e], ny = eyv[e], nz = ezv[e];
                float nc = nx * nx + ny * ny + nz * nz;
                float d0 = fmaf(q0x, nx, fmaf(q0y, ny, fmaf(q0z, nz, nc + q0w)));
                float d1 = fmaf(q1x, nx, fmaf(q1y, ny, fmaf(q1z, nz, nc + q1w)));
                d0reg[r * 4 + e] = d0;
                d1reg[r * 4 + e] = d1;
                vmin0 = fminf(vmin0, d0);
                vmin1 = fminf(vmin1, d1);
            }
        }

        float T[2];
#pragma unroll
        for (int t = 0; t < 2; ++t) {
            float v = t ? vmin1 : vmin0;
#pragma unroll
            for (int k = 2; k <= 64; k <<= 1) {
#pragma unroll
                for (int j = k >> 1; j > 0; j >>= 1) {
                    float o = __shfl_xor(v, j);
                    bool lower = (lane & j) == 0;
                    bool up = (lane & k) == 0;
                    float mn = fminf(v, o), mx = fmaxf(v, o);
                    v = (lower == up) ? mn : mx;
                }
            }
            T[t] = __shfl(v, 15);
        }
        __syncthreads();   // planes dead; surv alias safe

#pragma unroll
        for (int t = 0; t < 2; ++t) {
            float Tt = T[t];
            unsigned long long* buf = surv + (((w << 1) + t) << 7);
            unsigned cnt = 0;
#pragma unroll
            for (int s = 0; s < 64; ++s) {
                float d = t ? d1reg[s] : d0reg[s];
                bool hit = d <= Tt;
                unsigned long long mask = __ballot(hit);
                if (hit) {
                    unsigned off = cnt + (unsigned)__popcll(mask & ((1ull << lane) - 1ull));
                    if (off < 128) {
                        int j = ((s >> 2) * 64 + lane) * 4 + (s & 3);
                        buf[off] = ((unsigned long long)fmono(d) << 32) | (unsigned)j;
                    }
                }
                cnt += (unsigned)__popcll(mask);
            }
            if (cnt > 128) cnt = 128;

            unsigned long long v0 = (lane < (int)cnt) ? buf[lane] : 0xFFFFFFFFFFFFFFFFull;
            if (cnt <= 64) {
#pragma unroll
                for (int k = 2; k <= 64; k <<= 1) {
#pragma unroll
                    for (int j = k >> 1; j > 0; j >>= 1) {
                        bool lower = (lane & j) == 0;
                        bool up = (lane & k) == 0;
                        unsigned long long o0 = shfl_xor_u64(v0, j);
                        v0 = (lower == up) ? umin64(v0, o0) : umax64(v0, o0);
                    }
                }
            } else {
                unsigned long long v1 = (lane + 64 < (int)cnt) ? buf[lane + 64]
                                                               : 0xFFFFFFFFFFFFFFFFull;
#pragma unroll
                for (int k = 2; k <= 128; k <<= 1) {
#pragma unroll
                    for (int j = k >> 1; j > 0; j >>= 1) {
                        if (j >= 64) {
                            unsigned long long lo = umin64(v0, v1), hi = umax64(v0, v1);
                            v0 = lo; v1 = hi;
                        } else {
                            bool lower = (lane & j) == 0;
                            unsigned long long o0 = shfl_xor_u64(v0, j);
                            bool up0 = ((lane & k) == 0);
                            v0 = (lower == up0) ? umin64(v0, o0) : umax64(v0, o0);
                            unsigned long long o1 = shfl_xor_u64(v1, j);
                            bool up1 = (((64 + lane) & k) == 0);
                            v1 = (lower == up1) ? umin64(v1, o1) : umax64(v1, o1);
                        }
                    }
                }
            }
            if (lane < KNN)
                idx_out[((size_t)b * NN + n0 + t) * KNN + lane] =
                    (int)(unsigned)(v0 & 0xFFFFFFFFull);
        }
    } else if (blk < KNN_BLKS + PF_BLKS) {
        // ============ prep_features role: 4 waves, 16 points each ===========
        unsigned short* tl = (unsigned short*)smem + w * 16 * UPITCH;
        int g4 = (blk - KNN_BLKS) * 4 + w;   // 0..1023
        int b = g4 >> 8;
        int n0 = (g4 & 255) << 4;
        int m = lane & 15, quad = lane >> 4;
        size_t ybase = (size_t)b * CC * NN;

        short8 yA[2];
#pragma unroll
        for (int ks = 0; ks < 2; ++ks)
#pragma unroll
            for (int j = 0; j < 8; j += 2) {
                float a = y[ybase + (size_t)(ks * 32 + quad * 8 + j) * NN + n0 + m];
                float bq2 = y[ybase + (size_t)(ks * 32 + quad * 8 + j + 1) * NN + n0 + m];
                ((unsigned*)&yA[ks])[j >> 1] = pkbf(a, bq2);
            }

#pragma unroll
        for (int ot = 0; ot < 4; ++ot) {
            short8 bb0, bb1;
#pragma unroll
            for (int ks = 0; ks < 2; ++ks) {
                const float* wr = Ws + (ot * 16 + m) * CC + ks * 32 + quad * 8;
                float4 lo = *(const float4*)wr;
                float4 hi = *(const float4*)(wr + 4);
                short8 bb;
                ((unsigned*)&bb)[0] = pkbf(lo.x, lo.y);
                ((unsigned*)&bb)[1] = pkbf(lo.z, lo.w);
                ((unsigned*)&bb)[2] = pkbf(hi.x, hi.y);
                ((unsigned*)&bb)[3] = pkbf(hi.z, hi.w);
                if (ks == 0) bb0 = bb; else bb1 = bb;
            }
            floatx4 acc = (floatx4){0.f, 0.f, 0.f, 0.f};
            acc = __builtin_amdgcn_mfma_f32_16x16x32_bf16(yA[0], bb0, acc, 0, 0, 0);
            acc = __builtin_amdgcn_mfma_f32_16x16x32_bf16(yA[1], bb1, acc, 0, 0, 0);
            float bsv = bs[ot * 16 + m];
#pragma unroll
            for (int r = 0; r < 4; r += 2) {
                unsigned p2 = pkbf(acc[r] + bsv, acc[r + 1] + bsv);
                tl[(4 * quad + r) * UPITCH + ot * 16 + m] = (unsigned short)p2;
                tl[(4 * quad + r + 1) * UPITCH + ot * 16 + m] = (unsigned short)(p2 >> 16);
            }
        }
        __syncthreads();

        short8 uA[2];
#pragma unroll
        for (int ks = 0; ks < 2; ++ks)
            uA[ks] = lds_frag(&tl[m * UPITCH + ks * 32 + quad * 8]);

        // ---- swizzled copy-out: [point*64 + mcol*4 + nt] b64 stores ----
        int p = lane >> 2, gb = lane & 3;
        size_t obase = ((size_t)b * NN + n0 + p) * 64;
#pragma unroll
        for (int s = 0; s < 4; ++s) {
            int g = gb * 4 + s;   // mcol
            ushort4v pk;
#pragma unroll
            for (int nt = 0; nt < 4; ++nt)
                pk[nt] = tl[p * UPITCH + nt * 16 + g];
            *(ushort4v*)(y1bf + obase + g * 4) = pk;
        }
        __syncthreads();

#pragma unroll
        for (int ot = 0; ot < 4; ++ot) {
            short8 bb0, bb1;
#pragma unroll
            for (int ks = 0; ks < 2; ++ks) {
                const float* wr = Wk + (ot * 16 + m) * CC + ks * 32 + quad * 8;
                float4 lo = *(const float4*)wr;
                float4 hi = *(const float4*)(wr + 4);
                short8 bb;
                ((unsigned*)&bb)[0] = pkbf(lo.x, lo.y);
                ((unsigned*)&bb)[1] = pkbf(lo.z, lo.w);
                ((unsigned*)&bb)[2] = pkbf(hi.x, hi.y);
                ((unsigned*)&bb)[3] = pkbf(hi.z, hi.w);
                if (ks == 0) bb0 = bb; else bb1 = bb;
            }
            floatx4 acc = (floatx4){0.f, 0.f, 0.f, 0.f};
            acc = __builtin_amdgcn_mfma_f32_16x16x32_bf16(uA[0], bb0, acc, 0, 0, 0);
            acc = __builtin_amdgcn_mfma_f32_16x16x32_bf16(uA[1], bb1, acc, 0, 0, 0);
            float bkv = bk[ot * 16 + m];
#pragma unroll
            for (int r = 0; r < 4; r += 2) {
                unsigned p2 = pkbf(acc[r] + bkv, acc[r + 1] + bkv);
                tl[(4 * quad + r) * UPITCH + ot * 16 + m] = (unsigned short)p2;
                tl[(4 * quad + r + 1) * UPITCH + ot * 16 + m] = (unsigned short)(p2 >> 16);
            }
        }
        __syncthreads();
#pragma unroll
        for (int s = 0; s < 4; ++s) {
            int g = gb * 4 + s;
            ushort4v pk;
#pragma unroll
            for (int nt = 0; nt < 4; ++nt)
                pk[nt] = tl[p * UPITCH + nt * 16 + g];
            *(ushort4v*)(keybf + obase + g * 4) = pk;
        }

        // query = Wq*x + bq, computed directly in swizzled layout
        float x0 = x[(size_t)(b * 3 + 0) * NN + n0 + p];
        float x1 = x[(size_t)(b * 3 + 1) * NN + n0 + p];
        float x2 = x[(size_t)(b * 3 + 2) * NN + n0 + p];
#pragma unroll
        for (int s = 0; s < 4; ++s) {
            int g = gb * 4 + s;
            ushort4v pk;
#pragma unroll
            for (int nt = 0; nt < 4; ++nt) {
                int ch = nt * 16 + g;
                pk[nt] = f2bf(Wq[3 * ch + 0] * x0 + Wq[3 * ch + 1] * x1 +
                              Wq[3 * ch + 2] * x2 + bq[ch]);
            }
            *(ushort4v*)(qrybf + obase + g * 4) = pk;
        }
    } else {
        // ============ param-relayout role (32 blocks) ============
        int pb = blk - KNN_BLKS - PF_BLKS;
        int t0 = threadIdx.x;
        int t = pb * 256 + t0;
        const int stride = PP_BLKS * 256;
        if (pb == 0) {
            if (t0 < HH) {
                float s = g1[t0] * rsqrtf(v1[t0] + EPSV);
                float c = b1v[t0] - m1[t0] * s;
                P1p[4 * t0 + 0] = P1[3 * t0 + 0] * s;
                P1p[4 * t0 + 1] = P1[3 * t0 + 1] * s;
                P1p[4 * t0 + 2] = P1[3 * t0 + 2] * s;
                P1p[4 * t0 + 3] = pb1[t0] * s + c;
            }
            if (t0 < AH) {
                float s = g2[t0] * rsqrtf(v2[t0] + EPSV);
                bn2s_c[t0] = s;
                ab1f[t0] = ab1[t0] * s + (b2v[t0] - m2[t0] * s);
            }
        }
        for (int i = t; i < 16384; i += stride) {   // A1L (bn2 scale folded in)
            int e = i & 7, ln = (i >> 3) & 63, ks = (i >> 9) & 1, ht = i >> 10;
            int m = ln & 15, q = ln >> 4;
            int h = ht * 16 + m;
            float s = g2[h] * rsqrtf(v2[h] + EPSV);
            A1L[i] = f2bf(A1[h * CC + ks * 32 + q * 8 + e] * s);
        }
        for (int i = t; i < 16384; i += stride) {   // A2L (log2e folded in)
            int e = i & 7, ln = (i >> 3) & 63, kk = (i >> 9) & 7, nt = i >> 12;
            int m = ln & 15, q = ln >> 4;
            A2L[i] = f2bf(A2[(nt * 16 + m) * AH + kk * 32 + q * 8 + e] * LOG2E);
        }
        for (int i = t; i < 4096; i += stride) {    // P2L
            int e = i & 7, ln = (i >> 3) & 63, ks = (i >> 9) & 1, nt = i >> 10;
            int m = ln & 15, q = ln >> 4;
            P2L[i] = f2bf(P2[(nt * 16 + m) * HH + ks * 32 + q * 8 + e]);
        }
        for (int i = t; i < 4096; i += stride) {    // WendL
            int e = i & 7, ln = (i >> 3) & 63, ks = (i >> 9) & 1, wv = i >> 10;
            int m = ln & 15, q = ln >> 4;
            WendL[i] = f2bf(Wend[(wv * 16 + m) * CC + ks * 32 + q * 8 + e]);
        }
    }
}

// ---------------------------------------------------------------------------
// Kernel 2: fused MFMA attention v5. u_lds and hid_lds ALIAS one buffer:
// u_lds is dead once uA fragments are in registers, and hid has the identical
// per-wave footprint (rows w*32..w*32+31, pitch 68). LDS 39.4 -> 21.6 KB;
// __launch_bounds__(256,5) -> up to 5 blocks/CU (was 3). Wave-local access
// in lockstep + same memory object => compiler maintains read-before-write
// ordering via lgkmcnt; no extra barrier needed.
// ---------------------------------------------------------------------------
__global__ __launch_bounds__(256, 5) void attn_mfma(
    const float* __restrict__ x, const float* __restrict__ y,
    const unsigned short* __restrict__ y1bf, const unsigned short* __restrict__ keybf,
    const unsigned short* __restrict__ qrybf, const int* __restrict__ idx,
    const float* __restrict__ P1p, const unsigned short* __restrict__ P2L,
    const float* __restrict__ pb2, const unsigned short* __restrict__ A1L,
    const float* __restrict__ ab1f, const float* __restrict__ bn2s_c,
    const unsigned short* __restrict__ A2L, const unsigned short* __restrict__ WendL,
    const float* __restrict__ bend,
    float* __restrict__ out) {
    __shared__ unsigned short uh_lds[128 * UPITCH];   // u then hid (aliased)
    __shared__ float agg_lds[8 * 68];
    __shared__ float outstage[512];

    int blk = blockIdx.x;
    int b = blk & 3;
    int n0 = (blk >> 2) << 3;
    int w = threadIdx.x >> 6;
    int lane = threadIdx.x & 63;
    int m = lane & 15, quad = lane >> 4;

    int pt[2];
    size_t bpt[2];
#pragma unroll
    for (int t = 0; t < 2; ++t) {
        pt[t] = n0 + 2 * w + t;
        bpt[t] = (size_t)b * NN + pt[t];
    }

    // ---- gathers (b64 via swizzled layout), issued early ----
    int jm[2], j4[2][4];
    ushort4v qu4[2], y14[2], kv4[2][4];
#pragma unroll
    for (int t = 0; t < 2; ++t) {
        jm[t] = idx[bpt[t] * KNN + m];
#pragma unroll
        for (int r = 0; r < 4; ++r) j4[t][r] = idx[bpt[t] * KNN + 4 * quad + r];
        qu4[t] = *(const ushort4v*)(qrybf + bpt[t] * 64 + m * 4);
        y14[t] = *(const ushort4v*)(y1bf + bpt[t] * 64 + m * 4);
#pragma unroll
        for (int r = 0; r < 4; ++r)
            kv4[t][r] = *(const ushort4v*)(keybf + ((size_t)b * NN + j4[t][r]) * 64 + m * 4);
    }

    short8 h1A[2][2];
#pragma unroll
    for (int t = 0; t < 2; ++t) {
        float dx = x[(size_t)(b * 3 + 0) * NN + pt[t]] - x[(size_t)(b * 3 + 0) * NN + jm[t]];
        float dy = x[(size_t)(b * 3 + 1) * NN + pt[t]] - x[(size_t)(b * 3 + 1) * NN + jm[t]];
        float dz = x[(size_t)(b * 3 + 2) * NN + pt[t]] - x[(size_t)(b * 3 + 2) * NN + jm[t]];
#pragma unroll
        for (int ks = 0; ks < 2; ++ks)
#pragma unroll
            for (int j = 0; j < 8; j += 2) {
                int h1 = ks * 32 + quad * 8 + j;
                const float4 p0 = *(const float4*)(P1p + 4 * h1);
                const float4 p1 = *(const float4*)(P1p + 4 * h1 + 4);
                float a0 = fmaxf(p0.x * dx + p0.y * dy + p0.z * dz + p0.w, 0.f);
                float a1 = fmaxf(p1.x * dx + p1.y * dy + p1.z * dz + p1.w, 0.f);
                ((unsigned*)&h1A[t][ks])[j >> 1] = pkbf(a0, a1);
            }
    }

    floatx4 pacc[2][4];
#pragma unroll
    for (int t = 0; t < 2; ++t)
#pragma unroll
        for (int nt = 0; nt < 4; ++nt) pacc[t][nt] = (floatx4){0.f, 0.f, 0.f, 0.f};
#pragma unroll
    for (int ks = 0; ks < 2; ++ks)
#pragma unroll
        for (int nt = 0; nt < 4; ++nt) {
            short8 bb = *(const short8*)(P2L + ((nt * 2 + ks) * 64 + lane) * 8);
            pacc[0][nt] = __builtin_amdgcn_mfma_f32_16x16x32_bf16(h1A[0][ks], bb, pacc[0][nt], 0, 0, 0);
            pacc[1][nt] = __builtin_amdgcn_mfma_f32_16x16x32_bf16(h1A[1][ks], bb, pacc[1][nt], 0, 0, 0);
        }
#pragma unroll
    for (int nt = 0; nt < 4; ++nt) {
        float pb = pb2[nt * 16 + m];
#pragma unroll
        for (int t = 0; t < 2; ++t)
#pragma unroll
            for (int r = 0; r < 4; ++r) pacc[t][nt][r] += pb;
    }

    // ---- u = query - key + pe -> bf16 LDS (packed cvt) ----
#pragma unroll
    for (int t = 0; t < 2; ++t)
#pragma unroll
        for (int nt = 0; nt < 4; ++nt) {
            float qv = bf2f(qu4[t][nt]);
            float u0 = qv - bf2f(kv4[t][0][nt]) + pacc[t][nt][0];
            float u1 = qv - bf2f(kv4[t][1][nt]) + pacc[t][nt][1];
            float u2 = qv - bf2f(kv4[t][2][nt]) + pacc[t][nt][2];
            float u3 = qv - bf2f(kv4[t][3][nt]) + pacc[t][nt][3];
            unsigned p01 = pkbf(u0, u1), p23 = pkbf(u2, u3);
            int base = (w * 32 + t * 16 + 4 * quad) * UPITCH + nt * 16 + m;
            uh_lds[base + 0 * UPITCH] = (unsigned short)p01;
            uh_lds[base + 1 * UPITCH] = (unsigned short)(p01 >> 16);
            uh_lds[base + 2 * UPITCH] = (unsigned short)p23;
            uh_lds[base + 3 * UPITCH] = (unsigned short)(p23 >> 16);
        }

    short8 uA[2][2];
#pragma unroll
    for (int t = 0; t < 2; ++t)
#pragma unroll
        for (int ks = 0; ks < 2; ++ks)
            uA[t][ks] = lds_frag(&uh_lds[(w * 32 + t * 16 + m) * UPITCH + ks * 32 + quad * 8]);
    // uh_lds (u contents) now dead; reused for hidden tiles below.

    floatx4 acc2[2][4];
#pragma unroll
    for (int t = 0; t < 2; ++t)
#pragma unroll
        for (int nt = 0; nt < 4; ++nt) acc2[t][nt] = (floatx4){0.f, 0.f, 0.f, 0.f};

    for (int qd = 0; qd < 4; ++qd) {
#pragma unroll
        for (int nt4 = 0; nt4 < 4; ++nt4) {
            int ht = qd * 4 + nt4;
            const unsigned short* a1t = A1L + ht * 1024 + lane * 8;
            short8 b0 = *(const short8*)(a1t);
            short8 b1 = *(const short8*)(a1t + 512);
            int h = ht * 16 + m;
            float t0 = ab1f[h];
#pragma unroll
            for (int t = 0; t < 2; ++t) {
                floatx4 acc = (floatx4){0.f, 0.f, 0.f, 0.f};
                acc = __builtin_amdgcn_mfma_f32_16x16x32_bf16(uA[t][0], b0, acc, 0, 0, 0);
                acc = __builtin_amdgcn_mfma_f32_16x16x32_bf16(uA[t][1], b1, acc, 0, 0, 0);
                float h0 = fmaxf(acc[0] + t0, 0.f);
                float h1 = fmaxf(acc[1] + t0, 0.f);
                float h2 = fmaxf(acc[2] + t0, 0.f);
                float h3 = fmaxf(acc[3] + t0, 0.f);
                unsigned p01 = pkbf(h0, h1), p23 = pkbf(h2, h3);
                int base = (w * 32 + t * 16 + 4 * quad) * HPITCH + nt4 * 16 + m;
                uh_lds[base + 0 * HPITCH] = (unsigned short)p01;
                uh_lds[base + 1 * HPITCH] = (unsigned short)(p01 >> 16);
                uh_lds[base + 2 * HPITCH] = (unsigned short)p23;
                uh_lds[base + 3 * HPITCH] = (unsigned short)(p23 >> 16);
            }
        }
        short8 hA[2][2];
#pragma unroll
        for (int t = 0; t < 2; ++t)
#pragma unroll
            for (int ks = 0; ks < 2; ++ks)
                hA[t][ks] = lds_frag(&uh_lds[(w * 32 + t * 16 + m) * HPITCH + ks * 32 + quad * 8]);
#pragma unroll
        for (int ks = 0; ks < 2; ++ks)
#pragma unroll
            for (int nt = 0; nt < 4; ++nt) {
                int kk = qd * 2 + ks;
                short8 bb = *(const short8*)(A2L + ((nt * 8 + kk) * 64 + lane) * 8);
                acc2[0][nt] = __builtin_amdgcn_mfma_f32_16x16x32_bf16(hA[0][ks], bb, acc2[0][nt], 0, 0, 0);
                acc2[1][nt] = __builtin_amdgcn_mfma_f32_16x16x32_bf16(hA[1][ks], bb, acc2[1][nt], 0, 0, 0);
            }
    }

    // ---- softmax over 16 neighbors (logits pre-scaled by log2e -> exp2) ----
#pragma unroll
    for (int t = 0; t < 2; ++t)
#pragma unroll
        for (int nt = 0; nt < 4; ++nt) {
            float l0 = acc2[t][nt][0], l1 = acc2[t][nt][1];
            float l2 = acc2[t][nt][2], l3 = acc2[t][nt][3];
            float mx = fmaxf(fmaxf(l0, l1), fmaxf(l2, l3));
            mx = fmaxf(mx, __shfl_xor(mx, 16));
            mx = fmaxf(mx, __shfl_xor(mx, 32));
            float e0 = exp2f(l0 - mx), e1 = exp2f(l1 - mx);
            float e2 = exp2f(l2 - mx), e3 = exp2f(l3 - mx);
            float sum = (e0 + e1) + (e2 + e3);
            sum += __shfl_xor(sum, 16);
            sum += __shfl_xor(sum, 32);
            float y1v = bf2f(y14[t][nt]);
            float contrib = e0 * (y1v + pacc[t][nt][0]) + e1 * (y1v + pacc[t][nt][1]) +
                            e2 * (y1v + pacc[t][nt][2]) + e3 * (y1v + pacc[t][nt][3]);
            contrib += __shfl_xor(contrib, 16);
            contrib += __shfl_xor(contrib, 32);
            float agg = contrib / sum;
            if (quad == 0) agg_lds[(2 * w + t) * 68 + nt * 16 + m] = agg;
        }
    __syncthreads();

    short8 aggA[2];
#pragma unroll
    for (int ks = 0; ks < 2; ++ks)
#pragma unroll
        for (int j = 0; j < 8; j += 2) {
            float a0 = agg_lds[(m & 7) * 68 + ks * 32 + quad * 8 + j];
            float a1 = agg_lds[(m & 7) * 68 + ks * 32 + quad * 8 + j + 1];
            ((unsigned*)&aggA[ks])[j >> 1] = pkbf(a0, a1);
        }
    short8 wb0 = *(const short8*)(WendL + ((w * 2 + 0) * 64 + lane) * 8);
    short8 wb1 = *(const short8*)(WendL + ((w * 2 + 1) * 64 + lane) * 8);
    floatx4 facc = (floatx4){0.f, 0.f, 0.f, 0.f};
    facc = __builtin_amdgcn_mfma_f32_16x16x32_bf16(aggA[0], wb0, facc, 0, 0, 0);
    facc = __builtin_amdgcn_mfma_f32_16x16x32_bf16(aggA[1], wb1, facc, 0, 0, 0);
    if (quad < 2) {
        float be = bend[w * 16 + m];
#pragma unroll
        for (int r = 0; r < 4; ++r)
            outstage[(w * 16 + m) * 8 + 4 * quad + r] = facc[r] + be;
    }
    __syncthreads();

    int t2 = threadIdx.x;
    int o = t2 >> 2, pp = (t2 & 3) * 2;
#pragma unroll
    for (int e = 0; e < 2; ++e) {
        size_t oi = ((size_t)(b * CC + o)) * NN + n0 + pp + e;
        out[oi] = outstage[o * 8 + pp + e] + y[oi];
    }
}

// ---------------------------------------------------------------------------
extern "C" void kernel_launch(void* const* d_in, const int* in_sizes, int n_in,
                              void* d_out, int out_size, void* d_ws, size_t ws_size,
                              hipStream_t stream) {
    const float* x    = (const float*)d_in[0];
    const float* y    = (const float*)d_in[1];
    const float* Ws   = (const float*)d_in[2];
    const float* bs   = (const float*)d_in[3];
    const float* Wk   = (const float*)d_in[4];
    const float* bk   = (const float*)d_in[5];
    const float* Wq   = (const float*)d_in[6];
    const float* bq   = (const float*)d_in[7];
    const float* P1   = (const float*)d_in[8];
    const float* pb1  = (const float*)d_in[9];
    const float* g1   = (const float*)d_in[10];
    const float* b1   = (const float*)d_in[11];
    const float* m1   = (const float*)d_in[12];
    const float* v1   = (const float*)d_in[13];
    const float* P2   = (const float*)d_in[14];
    const float* pb2  = (const float*)d_in[15];
    const float* A1   = (const float*)d_in[16];
    const float* ab1  = (const float*)d_in[17];
    const float* g2   = (const float*)d_in[18];
    const float* b2   = (const float*)d_in[19];
    const float* m2   = (const float*)d_in[20];
    const float* v2   = (const float*)d_in[21];
    const float* A2   = (const float*)d_in[22];
    const float* ab2  = (const float*)d_in[23];  // dropped (softmax-invariant)
    const float* Wend = (const float*)d_in[24];
    const float* bend = (const float*)d_in[25];
    (void)ab2;

    unsigned short* usws = (unsigned short*)d_ws;
    unsigned short* y1bf  = usws;                  // 1,048,576 us (swizzled)
    unsigned short* keybf = usws + 1048576;        // 1,048,576 us (swizzled)
    unsigned short* qrybf = usws + 2097152;        // 1,048,576 us (swizzled)
    int* idx = (int*)(usws + 3145728);             // 262,144 ints
    unsigned short* A1L = usws + 3670016;          // 16,384 us
    unsigned short* A2L = A1L + 16384;             // 16,384 us
    unsigned short* P2L = A2L + 16384;             // 4,096 us
    unsigned short* WendL = P2L + 4096;            // 4,096 us
    float* P1p   = (float*)(WendL + 4096);         // 256 f (16B-aligned)
    float* ab1f  = P1p + 256;                      // 256 f
    float* bn2sc = ab1f + 256;                     // 256 f
    float* out   = (float*)d_out;

    hipLaunchKernelGGL(fused_prep_knn, dim3(KNN_BLKS + PF_BLKS + PP_BLKS), dim3(256), 0, stream,
                       x, y, Ws, bs, Wk, bk, Wq, bq,
                       P1, pb1, P2, A1, ab1, A2,
                       g1, b1, m1, v1, g2, b2, m2, v2, Wend,
                       idx, y1bf, keybf, qrybf,
                       A1L, A2L, P2L, WendL, P1p, ab1f, bn2sc);
    hipLaunchKernelGGL(attn_mfma, dim3(2048), dim3(256), 0, stream,
                       x, y, y1bf, keybf, qrybf, idx,
                       P1p, P2L, pb2, A1L, ab1f, bn2sc, A2L, WendL,
                       bend, out);
}